// Round 9
// baseline (765.929 us; speedup 1.0000x reference)
//
#include <hip/hip_runtime.h>
#include <math.h>

#define PS_CONST 0.31622776601683794f  // sqrt(0.1)

typedef __attribute__((ext_vector_type(8))) short short8;   // 8 bf16 (4 VGPRs)
typedef __attribute__((ext_vector_type(4))) float f32x4;

__device__ inline unsigned short f2b(float f) {
    unsigned u = __builtin_bit_cast(unsigned, f);
    unsigned r = (u + 0x7fffu + ((u >> 16) & 1u)) >> 16;   // RNE
    return (unsigned short)r;
}
__device__ inline float b2f(unsigned short b) {
    return __builtin_bit_cast(float, (unsigned)b << 16);
}

// fp32 -> bf16 elementwise (vectorized x4)
__global__ __launch_bounds__(256) void cvt_bf16_k(const float* __restrict__ in,
                                                  ushort* __restrict__ out, int n4)
{
    int idx = blockIdx.x * 256 + threadIdx.x;
    if (idx >= n4) return;
    float4 vv = ((const float4*)in)[idx];
    ushort4 o;
    o.x = f2b(vv.x); o.y = f2b(vv.y); o.z = f2b(vv.z); o.w = f2b(vv.w);
    ((ushort4*)out)[idx] = o;
}

// ---------------------------------------------------------------------------
// Fused: freq-add + hi/lo bf16 split + row(128) squared-norm.
// X: [B, L, 4, 128] fp32 (raw projection, no freq). F: freq table.
//   x' = X + PS * F[b, dupf ? 2l+1 : l, d]
//   hi/lo = bf16 split of x';  out2[(b*4+h)<<lishift | l] = sum_d x'^2
// One thread per float4; 32 consecutive threads cover one 128-d row.
// ---------------------------------------------------------------------------
__global__ __launch_bounds__(256) void freq_split_norm_k(
    const float* __restrict__ X, const float* __restrict__ F,
    ushort* __restrict__ hi, ushort* __restrict__ lo, float* __restrict__ out2,
    int lishift, int dupf)
{
    int idx = blockIdx.x * 256 + threadIdx.x;   // float4 index, exact multiple
    int f = idx << 2;
    int d = f & 127;
    int h = (f >> 7) & 3;
    int l = (f >> 9) & ((1 << lishift) - 1);
    int b = f >> (lishift + 9);
    int fr = dupf ? (2 * l + 1) : l;
    int fF = dupf ? (2 << lishift) : (1 << lishift);
    float4 xv = *(const float4*)&X[(size_t)f];
    float4 fv = *(const float4*)&F[((size_t)b * fF + fr) * 128 + d];
    float vs[4] = {xv.x + PS_CONST * fv.x, xv.y + PS_CONST * fv.y,
                   xv.z + PS_CONST * fv.z, xv.w + PS_CONST * fv.w};
    ushort4 hv, lv;
    unsigned short hb; float hf;
    hb = f2b(vs[0]); hf = b2f(hb); hv.x = hb; lv.x = f2b(vs[0] - hf);
    hb = f2b(vs[1]); hf = b2f(hb); hv.y = hb; lv.y = f2b(vs[1] - hf);
    hb = f2b(vs[2]); hf = b2f(hb); hv.z = hb; lv.z = f2b(vs[2] - hf);
    hb = f2b(vs[3]); hf = b2f(hb); hv.w = hb; lv.w = f2b(vs[3] - hf);
    ((ushort4*)hi)[idx] = hv;
    ((ushort4*)lo)[idx] = lv;
    float s = vs[0] * vs[0] + vs[1] * vs[1] + vs[2] * vs[2] + vs[3] * vs[3];
    #pragma unroll
    for (int off = 16; off > 0; off >>= 1) s += __shfl_xor(s, off);  // 32-lane row group
    if ((threadIdx.x & 31) == 0)
        out2[(((size_t)b * 4 + h) << lishift) + l] = s;
}

// weight transform: out[c][tap*512 + i] = bf16(w[c][i][3] at [c*1536 + i*3 + tap])
__global__ __launch_bounds__(256) void wcvt_k(const float* __restrict__ w,
                                              ushort* __restrict__ out)
{
    int idx = blockIdx.x * 256 + threadIdx.x;   // 786432
    if (idx >= 786432) return;
    int c = idx / 1536;
    int rem = idx - c * 1536;
    int tap = rem >> 9, i = rem & 511;
    out[idx] = f2b(w[c * 1536 + i * 3 + tap]);
}

// fused bf16 cast of the four 512x512 projection weights
__global__ __launch_bounds__(256) void wcvt4_k(
    const float* __restrict__ w0, const float* __restrict__ w1,
    const float* __restrict__ w2, const float* __restrict__ w3,
    ushort* __restrict__ o0, ushort* __restrict__ o1,
    ushort* __restrict__ o2, ushort* __restrict__ o3)
{
    int idx = blockIdx.x * 256 + threadIdx.x;   // 4 * 65536 float4
    int sel = idx >> 16, off = idx & 65535;
    const float* w = (sel == 0) ? w0 : (sel == 1) ? w1 : (sel == 2) ? w2 : w3;
    ushort* o = (sel == 0) ? o0 : (sel == 1) ? o1 : (sel == 2) ? o2 : o3;
    float4 vv = ((const float4*)w)[off];
    ushort4 r;
    r.x = f2b(vv.x); r.y = f2b(vv.y); r.z = f2b(vv.z); r.w = f2b(vv.w);
    ((ushort4*)o)[off] = r;
}

// Toeplitz A-fragment precompute for score conv MFMA.
__global__ __launch_bounds__(256) void atoep_k(const float* __restrict__ sw,
                                               ushort* __restrict__ At)
{
    int idx = blockIdx.x * 256 + threadIdx.x;   // 81920
    if (idx >= 81920) return;
    int t = idx & 7;
    int lane = (idx >> 3) & 63;
    int ks = (idx >> 9) & 1;
    int rem = idx >> 10;        // 0..79
    int dj = rem % 5, ohi = rem / 5;
    int m = lane & 15;
    int k = ks * 32 + ((lane >> 4) << 3) + t;
    int d = k - m;
    float val = (d >= 0 && d < 45) ? sw[(ohi * 45 + d) * 5 + dj] : 0.f;
    At[idx] = f2b(val);
}

// ---------------------------------------------------------------------------
// conv1d(512->512,k3,SAME) + bias + silu as MFMA bf16 GEMM.
// ---------------------------------------------------------------------------
__global__ __launch_bounds__(256) void conv_mfma(
    const ushort* __restrict__ xtb, const ushort* __restrict__ wtb,
    const float* __restrict__ cb, float* __restrict__ z, int L)
{
    __shared__ __align__(16) ushort Ash[128 * 40];
    __shared__ __align__(16) ushort Bsh[128 * 40];
    const int b = blockIdx.z;
    const int cm = blockIdx.y << 7;
    const int l0 = blockIdx.x << 7;
    const int tid = threadIdx.x;
    const int wave = tid >> 6, lane = tid & 63;
    const int wm = (wave & 1) << 6, wn = (wave >> 1) << 6;
    const int lo16 = lane & 15, hi4 = lane >> 4;

    f32x4 acc[4][4];
    #pragma unroll
    for (int i = 0; i < 4; i++)
        #pragma unroll
        for (int j = 0; j < 4; j++)
            acc[i][j] = (f32x4){0.f, 0.f, 0.f, 0.f};

    for (int k0 = 0; k0 < 1536; k0 += 32) {
        const int tap = k0 >> 9;
        const int cbase = k0 & 511;
        {
            int u = tid;
            #pragma unroll
            for (int p = 0; p < 2; p++, u += 256) {
                int row = u >> 2, g = (u & 3) << 3;
                *(uint4*)&Ash[row * 40 + g] =
                    *(const uint4*)&wtb[(size_t)(cm + row) * 1536 + k0 + g];
            }
        }
        {
            int u = tid;
            #pragma unroll
            for (int p = 0; p < 2; p++, u += 256) {
                int row = u >> 2, g = (u & 3) << 3;
                int lg = l0 + tap - 1 + row;
                uint4 val = make_uint4(0u, 0u, 0u, 0u);
                if (lg >= 0 && lg < L)
                    val = *(const uint4*)&xtb[((size_t)b * L + lg) * 512 + cbase + g];
                *(uint4*)&Bsh[row * 40 + g] = val;
            }
        }
        __syncthreads();
        short8 a[4], bb[4];
        #pragma unroll
        for (int t = 0; t < 4; t++) {
            a[t]  = *(const short8*)&Ash[(wm + t * 16 + lo16) * 40 + hi4 * 8];
            bb[t] = *(const short8*)&Bsh[(wn + t * 16 + lo16) * 40 + hi4 * 8];
        }
        #pragma unroll
        for (int mt = 0; mt < 4; mt++)
            #pragma unroll
            for (int nt = 0; nt < 4; nt++)
                acc[mt][nt] = __builtin_amdgcn_mfma_f32_16x16x32_bf16(
                    a[mt], bb[nt], acc[mt][nt], 0, 0, 0);
        __syncthreads();
    }
    #pragma unroll
    for (int mt = 0; mt < 4; mt++) {
        #pragma unroll
        for (int r = 0; r < 4; r++) {
            int c = cm + wm + mt * 16 + hi4 * 4 + r;
            float bias = cb[c];
            #pragma unroll
            for (int nt = 0; nt < 4; nt++) {
                int l = l0 + wn + nt * 16 + lo16;
                float u = acc[mt][nt][r] + bias;
                u = u / (1.f + __expf(-u));
                z[((size_t)b * 512 + c) * L + l] = u;
            }
        }
    }
}

// ---------------------------------------------------------------------------
// Y[M,N] fp32 = Xb[M,K]bf16 @ Wb[N,K]bf16^T (+bias), MFMA, 128x128 tile.
// dup: write row m -> rows 2m, 2m+1.
// ---------------------------------------------------------------------------
__global__ __launch_bounds__(256) void gemm_mfma_bf16(
    const ushort* __restrict__ Xb, const ushort* __restrict__ Wb,
    const float* __restrict__ bias, float* __restrict__ Y,
    int M, int N, int K, int dup)
{
    __shared__ __align__(16) ushort Ash[128 * 40];
    __shared__ __align__(16) ushort Bsh[128 * 40];
    const int bm = blockIdx.y << 7, bn = blockIdx.x << 7;
    const int tid = threadIdx.x;
    const int wave = tid >> 6, lane = tid & 63;
    const int wm = (wave & 1) << 6, wn = (wave >> 1) << 6;
    const int lo16 = lane & 15, hi4 = lane >> 4;

    f32x4 acc[4][4];
    #pragma unroll
    for (int i = 0; i < 4; i++)
        #pragma unroll
        for (int j = 0; j < 4; j++)
            acc[i][j] = (f32x4){0.f, 0.f, 0.f, 0.f};

    for (int k0 = 0; k0 < K; k0 += 32) {
        int u = tid;
        #pragma unroll
        for (int p = 0; p < 2; p++, u += 256) {
            int row = u >> 2, g = (u & 3) << 3;
            *(uint4*)&Ash[row * 40 + g] =
                *(const uint4*)&Xb[(size_t)(bm + row) * K + k0 + g];
            *(uint4*)&Bsh[row * 40 + g] =
                *(const uint4*)&Wb[(size_t)(bn + row) * K + k0 + g];
        }
        __syncthreads();
        short8 a[4], bb[4];
        #pragma unroll
        for (int t = 0; t < 4; t++) {
            a[t]  = *(const short8*)&Ash[(wm + t * 16 + lo16) * 40 + hi4 * 8];
            bb[t] = *(const short8*)&Bsh[(wn + t * 16 + lo16) * 40 + hi4 * 8];
        }
        #pragma unroll
        for (int mt = 0; mt < 4; mt++)
            #pragma unroll
            for (int nt = 0; nt < 4; nt++)
                acc[mt][nt] = __builtin_amdgcn_mfma_f32_16x16x32_bf16(
                    a[mt], bb[nt], acc[mt][nt], 0, 0, 0);
        __syncthreads();
    }
    #pragma unroll
    for (int mt = 0; mt < 4; mt++) {
        #pragma unroll
        for (int r = 0; r < 4; r++) {
            int m = bm + wm + mt * 16 + hi4 * 4 + r;
            #pragma unroll
            for (int nt = 0; nt < 4; nt++) {
                int n = bn + wn + nt * 16 + lo16;
                float val = acc[mt][nt][r];
                if (bias) val += bias[n];
                if (dup) {
                    Y[(size_t)(2 * m)     * N + n] = val;
                    Y[(size_t)(2 * m + 1) * N + n] = val;
                } else {
                    Y[(size_t)m * N + n] = val;
                }
            }
        }
    }
}

// per-column LN stats over 512 channels: stats[b][l] = (mean, rsqrt(var+eps))
__global__ __launch_bounds__(256) void ln_stats_k(const float* __restrict__ z,
                                                  float2* __restrict__ stats, int L)
{
    __shared__ float s_sh[4][64];
    __shared__ float s2_sh[4][64];
    const int b = blockIdx.y;
    const int colL = threadIdx.x & 63;
    const int col = (blockIdx.x << 6) + colL;
    const int part = threadIdx.x >> 6;
    const float* base = z + ((size_t)b * 512 + part * 128) * L + col;
    float s = 0.f, s2 = 0.f;
    for (int i = 0; i < 128; i++) {
        float vv = base[(size_t)i * L];
        s += vv; s2 += vv * vv;
    }
    s_sh[part][colL] = s; s2_sh[part][colL] = s2;
    __syncthreads();
    if (threadIdx.x < 64) {
        float ts = 0.f, ts2 = 0.f;
        #pragma unroll
        for (int p = 0; p < 4; p++) { ts += s_sh[p][colL]; ts2 += s2_sh[p][colL]; }
        float m = ts * (1.f / 512.f);
        float var = ts2 * (1.f / 512.f) - m * m;
        stats[(size_t)b * L + col] = make_float2(m, rsqrtf(var + 1e-5f));
    }
}

// LN apply + maxpool(k3,s2,pad -inf): out[b][c][lp], Lout = L/2 = 1<<lshift
__global__ __launch_bounds__(256) void ln_maxpool_k(
    const float* __restrict__ z, const float2* __restrict__ stats,
    const float* __restrict__ g, const float* __restrict__ be,
    float* __restrict__ out, int L, int lshift)
{
    const int Lout = 1 << lshift;
    size_t idx = (size_t)blockIdx.x * 256 + threadIdx.x;  // 8*512*Lout
    int lp = (int)(idx & (Lout - 1));
    int c = (int)((idx >> lshift) & 511);
    int b = (int)(idx >> (lshift + 9));
    const float* zp = z + ((size_t)b * 512 + c) * L;
    const float2* sp = stats + (size_t)b * L;
    float gc = g[c], bc = be[c];
    int l = lp << 1;
    float2 st = sp[l];
    float m = (zp[l] - st.x) * st.y * gc + bc;
    if (l > 0) {
        float2 s0 = sp[l - 1];
        m = fmaxf(m, (zp[l - 1] - s0.x) * s0.y * gc + bc);
    }
    float2 s1 = sp[l + 1];
    m = fmaxf(m, (zp[l + 1] - s1.x) * s1.y * gc + bc);
    out[idx] = m;
}

// x0 [B][512][1024] fp32 -> x0tb [B][1024][512] bf16 (tiled transpose + cvt)
__global__ __launch_bounds__(256) void transpose_cvt_k(const float* __restrict__ x0,
                                                       ushort* __restrict__ xtb)
{
    __shared__ ushort t[32][33];
    const int b = blockIdx.z, c0 = blockIdx.y << 5, l0 = blockIdx.x << 5;
    const int col = threadIdx.x & 31, r0 = threadIdx.x >> 5;
    #pragma unroll
    for (int p = 0; p < 4; p++) {
        int r = r0 + p * 8;
        t[r][col] = f2b(x0[((size_t)b * 512 + c0 + r) * 1024 + l0 + col]);
    }
    __syncthreads();
    #pragma unroll
    for (int p = 0; p < 4; p++) {
        int r = r0 + p * 8;
        xtb[((size_t)b * 1024 + l0 + r) * 512 + c0 + col] = t[col][r];
    }
}

// vTb[bh][d][j] bf16 = v[b][j][h][d]  (tiled transpose + cvt, per head)
__global__ __launch_bounds__(256) void vT_cvt_k(const float* __restrict__ v,
                                                ushort* __restrict__ vTb)
{
    __shared__ ushort t[32][33];
    const int bh = blockIdx.z, b = bh >> 2, h = bh & 3;
    const int d0 = blockIdx.y << 5, j0 = blockIdx.x << 5;
    const int col = threadIdx.x & 31, r0 = threadIdx.x >> 5;
    #pragma unroll
    for (int p = 0; p < 4; p++) {
        int r = r0 + p * 8;   // j offset
        t[r][col] = f2b(v[(((size_t)b * 512 + j0 + r) * 4 + h) * 128 + d0 + col]);
    }
    __syncthreads();
    #pragma unroll
    for (int p = 0; p < 4; p++) {
        int r = r0 + p * 8;   // d offset
        vTb[((size_t)bh * 128 + d0 + r) * 512 + j0 + col] = t[col][r];
    }
}

// qxb[b, l, c] = bf16( x0[b, c, l] + x1[b, c, l>>1] )  (upsample-add + transpose + cast)
__global__ __launch_bounds__(256) void upsample_add_t(const float* __restrict__ x0,
    const float* __restrict__ x1, ushort* __restrict__ qxb)
{
    size_t idx = (size_t)blockIdx.x * 256 + threadIdx.x;  // 8*1024*512
    int c = (int)(idx & 511);
    int l = (int)((idx >> 9) & 1023);
    int b = (int)(idx >> 19);
    qxb[idx] = f2b(x0[((size_t)b * 512 + c) * 1024 + l] +
                   x1[((size_t)b * 512 + c) * 512 + (l >> 1)]);
}

// ---------------------------------------------------------------------------
// Gaussian scores via bf16 MFMA with hi/lo error compensation.
// attn0[bh,i,j] = -clip((q2+k2-2*q.k)/128, 0) / temp[h]
// Dual-write: fp32 attn0 (for conv residual) + bf16 attn0b (for conv staging).
// ---------------------------------------------------------------------------
__global__ __launch_bounds__(256) void scores_mfma(
    const ushort* __restrict__ qhi, const ushort* __restrict__ qlo,
    const ushort* __restrict__ khi, const ushort* __restrict__ klo,
    const float* __restrict__ q2, const float* __restrict__ k2,
    float* __restrict__ attn0, ushort* __restrict__ attn0b)
{
    __shared__ __align__(16) ushort Ah[128 * 40];
    __shared__ __align__(16) ushort Al[128 * 40];
    __shared__ __align__(16) ushort Bh[128 * 40];
    __shared__ __align__(16) ushort Bl[128 * 40];
    const int bh = blockIdx.z, b = bh >> 2, h = bh & 3;
    const int bm = blockIdx.y << 7, bn = blockIdx.x << 7;
    const int tid = threadIdx.x;
    const int wave = tid >> 6, lane = tid & 63;
    const int wm = (wave & 1) << 6, wn = (wave >> 1) << 6;
    const int lo16 = lane & 15, hi4 = lane >> 4;

    f32x4 acc[4][4];
    #pragma unroll
    for (int i = 0; i < 4; i++)
        #pragma unroll
        for (int j = 0; j < 4; j++)
            acc[i][j] = (f32x4){0.f, 0.f, 0.f, 0.f};

    for (int k0 = 0; k0 < 128; k0 += 32) {
        int u = tid;
        #pragma unroll
        for (int p = 0; p < 2; p++, u += 256) {
            int row = u >> 2, g = (u & 3) << 3;
            size_t aoff = (((size_t)b * 1024 + bm + row) * 4 + h) * 128 + k0 + g;
            size_t boff = (((size_t)b * 512  + bn + row) * 4 + h) * 128 + k0 + g;
            *(uint4*)&Ah[row * 40 + g] = *(const uint4*)&qhi[aoff];
            *(uint4*)&Al[row * 40 + g] = *(const uint4*)&qlo[aoff];
            *(uint4*)&Bh[row * 40 + g] = *(const uint4*)&khi[boff];
            *(uint4*)&Bl[row * 40 + g] = *(const uint4*)&klo[boff];
        }
        __syncthreads();
        short8 ah[4], al[4], bhF[4], blF[4];
        #pragma unroll
        for (int t = 0; t < 4; t++) {
            int ar = (wm + t * 16 + lo16) * 40 + hi4 * 8;
            int br = (wn + t * 16 + lo16) * 40 + hi4 * 8;
            ah[t]  = *(const short8*)&Ah[ar];
            al[t]  = *(const short8*)&Al[ar];
            bhF[t] = *(const short8*)&Bh[br];
            blF[t] = *(const short8*)&Bl[br];
        }
        #pragma unroll
        for (int mt = 0; mt < 4; mt++)
            #pragma unroll
            for (int nt = 0; nt < 4; nt++) {
                acc[mt][nt] = __builtin_amdgcn_mfma_f32_16x16x32_bf16(
                    ah[mt], bhF[nt], acc[mt][nt], 0, 0, 0);
                acc[mt][nt] = __builtin_amdgcn_mfma_f32_16x16x32_bf16(
                    ah[mt], blF[nt], acc[mt][nt], 0, 0, 0);
                acc[mt][nt] = __builtin_amdgcn_mfma_f32_16x16x32_bf16(
                    al[mt], bhF[nt], acc[mt][nt], 0, 0, 0);
            }
        __syncthreads();
    }
    const float it = (h == 0) ? 1.f : (h == 1) ? 0.25f : (h == 2) ? (1.f / 7.f) : 0.1f;
    #pragma unroll
    for (int mt = 0; mt < 4; mt++) {
        #pragma unroll
        for (int r = 0; r < 4; r++) {
            int i = bm + wm + mt * 16 + hi4 * 4 + r;
            float q2v = q2[(size_t)bh * 1024 + i];
            #pragma unroll
            for (int nt = 0; nt < 4; nt++) {
                int j = bn + wn + nt * 16 + lo16;
                float d2 = q2v + k2[(size_t)bh * 512 + j] - 2.f * acc[mt][nt][r];
                d2 *= (1.f / 128.f);
                if (d2 < 0.f) d2 = 0.f;
                float sc = -d2 * it;
                size_t off = ((size_t)bh * 1024 + i) * 512 + j;
                attn0[off]  = sc;
                attn0b[off] = f2b(sc);
            }
        }
    }
}

// ---------------------------------------------------------------------------
// Conv2d(4,4,(45,5),pad(22,2)) via MFMA (Toeplitz along i).
// j-tile 32, 4 blocks/CU; staging from bf16 attn0b.
// dj loop unrolled so the compiler pipelines At/LDS loads under MFMA.
// ---------------------------------------------------------------------------
__global__ __launch_bounds__(256) void score_conv_mfma(
    const float* __restrict__ attn0, const ushort* __restrict__ attn0b,
    const ushort* __restrict__ At, const float* __restrict__ sb,
    const float* __restrict__ mask, float* __restrict__ attn1)
{
    __shared__ __align__(16) ushort tileT[4 * 36 * 120];   // [hi][jj][ii], ii stride 120
    const int b = blockIdx.z, i0 = blockIdx.y << 6, j0 = blockIdx.x << 5;
    const int tid = threadIdx.x, wave = tid >> 6, lane = tid & 63;

    for (int idx = tid; idx < 4 * 36 * 56; idx += 256) {
        int jj = idx % 36;
        int r2 = idx / 36;
        int ip = r2 % 56, hi = r2 / 56;
        int ii = ip << 1;
        int gi = i0 - 22 + ii, gj = j0 - 2 + jj;
        const ushort* src = attn0b + ((size_t)(b * 4 + hi) * 1024 + gi) * 512 + gj;
        bool jv = (unsigned)gj < 512u;
        unsigned v0 = (jv && (unsigned)gi       < 1024u) ? (unsigned)src[0]   : 0u;
        unsigned v1 = (jv && (unsigned)(gi + 1) < 1024u) ? (unsigned)src[512] : 0u;
        *(unsigned*)&tileT[(hi * 36 + jj) * 120 + ii] = v0 | (v1 << 16);
    }
    __syncthreads();

    const int n16 = lane & 15, quad = lane >> 4;
    f32x4 acc[4][2];
    #pragma unroll
    for (int o = 0; o < 4; o++)
        #pragma unroll
        for (int t = 0; t < 2; t++)
            acc[o][t] = (f32x4){0.f, 0.f, 0.f, 0.f};

    const int iibase = wave * 16 + quad * 8;
    #pragma unroll 1
    for (int hi = 0; hi < 4; hi++) {
        #pragma unroll
        for (int dj = 0; dj < 5; dj++) {
            #pragma unroll
            for (int ks = 0; ks < 2; ks++) {
                short8 bf[2];
                #pragma unroll
                for (int t = 0; t < 2; t++)
                    bf[t] = *(const short8*)&tileT[(hi * 36 + t * 16 + n16 + dj) * 120
                                                   + iibase + ks * 32];
                #pragma unroll
                for (int o = 0; o < 4; o++) {
                    short8 af = *(const short8*)&At[((((o * 4 + hi) * 5 + dj) * 2 + ks) * 64
                                                     + lane) * 8];
                    #pragma unroll
                    for (int t = 0; t < 2; t++)
                        acc[o][t] = __builtin_amdgcn_mfma_f32_16x16x32_bf16(
                            af, bf[t], acc[o][t], 0, 0, 0);
                }
            }
        }
    }

    #pragma unroll
    for (int o = 0; o < 4; o++) {
        float bo = sb[o];
        #pragma unroll
        for (int r = 0; r < 4; r++) {
            int i = i0 + wave * 16 + quad * 4 + r;
            size_t obase = ((size_t)(b * 4 + o) * 1024 + i) * 512;
            size_t mbase = ((size_t)b * 1024 + i) * 512;
            #pragma unroll
            for (int t = 0; t < 2; t++) {
                int j = j0 + t * 16 + n16;
                attn1[obase + j] = attn0[obase + j] + acc[o][t][r] + bo + mask[mbase + j];
            }
        }
    }
}

// softmax(row) -> clip -> * clip(prior) -> renorm; write rows 2i,2i+1 fp32
// plus a non-duplicated bf16 plane for the attn@v MFMA.
__global__ __launch_bounds__(256) void softmax_prior_k(
    const float* __restrict__ attn1, const float* __restrict__ prior,
    float* __restrict__ attn_out, ushort* __restrict__ ab)
{
    const int wid = threadIdx.x >> 6, lane = threadIdx.x & 63;
    size_t row = (size_t)blockIdx.x * 4 + wid;   // 0..32767
    int i = (int)(row & 1023);
    int bh = (int)(row >> 10);
    int b = bh >> 2;
    const float* arow = attn1 + row * 512;
    const float* prow = prior + ((size_t)b * 2048 + 2 * i + 1) * 512;
    float v[8], p[8];
    #pragma unroll
    for (int t = 0; t < 8; t++) {
        v[t] = arow[lane + 64 * t];
        p[t] = prow[lane + 64 * t];
    }
    float mx = v[0];
    #pragma unroll
    for (int t = 1; t < 8; t++) mx = fmaxf(mx, v[t]);
    #pragma unroll
    for (int off = 32; off > 0; off >>= 1) mx = fmaxf(mx, __shfl_xor(mx, off));
    float sum = 0.f;
    #pragma unroll
    for (int t = 0; t < 8; t++) { v[t] = expf(v[t] - mx); sum += v[t]; }
    #pragma unroll
    for (int off = 32; off > 0; off >>= 1) sum += __shfl_xor(sum, off);
    float inv = 1.f / sum;
    float sum2 = 0.f;
    #pragma unroll
    for (int t = 0; t < 8; t++) {
        float sm = fmaxf(v[t] * inv, 1e-8f);
        float pr = fmaxf(p[t], 1e-8f);
        v[t] = sm * pr;
        sum2 += v[t];
    }
    #pragma unroll
    for (int off = 32; off > 0; off >>= 1) sum2 += __shfl_xor(sum2, off);
    float inv2 = 1.f / (sum2 + 1e-8f);
    float* o0 = attn_out + ((size_t)bh * 2048 + 2 * i) * 512;
    ushort* abrow = ab + row * 512;
    #pragma unroll
    for (int t = 0; t < 8; t++) {
        float val = v[t] * inv2;
        o0[lane + 64 * t] = val;
        o0[512 + lane + 64 * t] = val;
        abrow[lane + 64 * t] = f2b(val);
    }
}

// ---------------------------------------------------------------------------
// attn @ v via bf16 MFMA from the non-duplicated bf16 plane:
// xpb[b,i,h*128+d] = bf16( sum_j ab[bh,i,j] * vT[bh,d,j] )
// M=1024 (i), N=128 (d, covered by waves), K=512 (j). Grid (1, 8, 32).
// ---------------------------------------------------------------------------
__global__ __launch_bounds__(256) void attnv_mfma(
    const ushort* __restrict__ ab, const ushort* __restrict__ vTb,
    ushort* __restrict__ xpb)
{
    __shared__ __align__(16) ushort Ash[128 * 40];
    __shared__ __align__(16) ushort Bsh[128 * 40];
    const int bh = blockIdx.z, b = bh >> 2, h = bh & 3;
    const int bm = blockIdx.y << 7;
    const ushort* A = ab + (size_t)bh * 1024 * 512;
    const ushort* B = vTb + (size_t)bh * 128 * 512;
    const int tid = threadIdx.x;
    const int wave = tid >> 6, lane = tid & 63;
    const int wm = (wave & 1) << 6, wn = (wave >> 1) << 6;
    const int lo16 = lane & 15, hi4 = lane >> 4;

    f32x4 acc[4][4];
    #pragma unroll
    for (int i = 0; i < 4; i++)
        #pragma unroll
        for (int j = 0; j < 4; j++)
            acc[i][j] = (f32x4){0.f, 0.f, 0.f, 0.f};

    for (int k0 = 0; k0 < 512; k0 += 32) {
        int u = tid;
        #pragma unroll
        for (int p = 0; p < 2; p++, u += 256) {
            int row = u >> 2, g = (u & 3) << 3;
            *(uint4*)&Ash[row * 40 + g] = *(const uint4*)&A[(size_t)(bm + row) * 512 + k0 + g];
            *(uint4*)&Bsh[row * 40 + g] = *(const uint4*)&B[(size_t)row * 512 + k0 + g];
        }
        __syncthreads();
        short8 a[4], bb[4];
        #pragma unroll
        for (int t = 0; t < 4; t++) {
            a[t]  = *(const short8*)&Ash[(wm + t * 16 + lo16) * 40 + hi4 * 8];
            bb[t] = *(const short8*)&Bsh[(wn + t * 16 + lo16) * 40 + hi4 * 8];
        }
        #pragma unroll
        for (int mt = 0; mt < 4; mt++)
            #pragma unroll
            for (int nt = 0; nt < 4; nt++)
                acc[mt][nt] = __builtin_amdgcn_mfma_f32_16x16x32_bf16(
                    a[mt], bb[nt], acc[mt][nt], 0, 0, 0);
        __syncthreads();
    }
    #pragma unroll
    for (int mt = 0; mt < 4; mt++) {
        #pragma unroll
        for (int r = 0; r < 4; r++) {
            int m = bm + wm + mt * 16 + hi4 * 4 + r;
            #pragma unroll
            for (int nt = 0; nt < 4; nt++) {
                int n = wn + nt * 16 + lo16;
                xpb[((size_t)b * 1024 + m) * 512 + h * 128 + n] = f2b(acc[mt][nt][r]);
            }
        }
    }
}

extern "C" void kernel_launch(void* const* d_in, const int* in_sizes, int n_in,
                              void* d_out, int out_size, void* d_ws, size_t ws_size,
                              hipStream_t stream)
{
    const float* q_x    = (const float*)d_in[0];
    const float* kv_x   = (const float*)d_in[1];
    const float* qf     = (const float*)d_in[2];
    const float* kf     = (const float*)d_in[3];
    const float* mask   = (const float*)d_in[4];
    const float* prior  = (const float*)d_in[5];
    const float* qds_w  = (const float*)d_in[6];
    const float* qds_b  = (const float*)d_in[7];
    const float* qds_g  = (const float*)d_in[8];
    const float* qds_be = (const float*)d_in[9];
    const float* qp_w   = (const float*)d_in[10];   // only layer 0 used (xs[2] is dead)
    const float* qp_b   = (const float*)d_in[11];
    const float* qp_g   = (const float*)d_in[12];
    const float* qp_be  = (const float*)d_in[13];
    const float* wq     = (const float*)d_in[14];
    const float* wk     = (const float*)d_in[15];
    const float* wv     = (const float*)d_in[16];
    const float* sw     = (const float*)d_in[17];
    const float* sb     = (const float*)d_in[18];
    const float* pw     = (const float*)d_in[19];
    const float* pb     = (const float*)d_in[20];

    if (ws_size < (size_t)56672256 * 4) return;
    float* ws = (float*)d_ws;
    float* z     = ws;               // [8,512,2048]; later qxb, then qhi/qlo
    float* x0    = ws + 8388608;     // [8,512,1024]; later At + weights + khi/klo/vTb
    float* x1    = ws + 12582912;    // [8,512,512];  later kvb (bf16)
    float* q     = ws + 14680064;    // [8,1024,4,128]; later attn0b (with k,v regions)
    float* k     = ws + 18874368;    // [8,512,4,128]
    float* v     = ws + 20971520;    // [8,512,4,128]
    float* q2    = ws + 23068672;    // [32,1024]
    float* k2    = ws + 23101440;    // [32,512]
    float* attn0 = ws + 23117824;    // [8,4,1024,512]; later xpb + ab (bf16)
    float* attn1 = ws + 39895040;    // [8,4,1024,512]
    // early-phase buffers aliased INSIDE attn1 region (dead before score_conv writes attn1)
    ushort* xtb   = (ushort*)(ws + 39895040);            // [8,2048,512] bf16
    ushort* x0tb  = (ushort*)(ws + 39895040 + 4194304);  // [8,1024,512] bf16
    ushort* wc1b  = (ushort*)(ws + 39895040 + 6291456);  // [512,1536] bf16
    ushort* wc2b  = (ushort*)(ws + 39895040 + 6684672);  // [512,1536] bf16
    float2* stats1 = (float2*)(ws + 39895040 + 7077888); // [8,2048]
    float2* stats2 = (float2*)(ws + 39895040 + 7110656); // [8,1024]
    // mid-phase bf16 buffers in the dead x0/z/x1 regions (float offsets, all disjoint):
    //   At    8388608..8429568 | wqb 8454144..8585216 | wkb ..8716288 | wvb ..8847360
    //   pwb   8847360..8978432 | khi 8978432..10027008 | klo ..11075584 | vTb ..12124160
    ushort* qxb  = (ushort*)z;                 // [8,1024,512] bf16 (z dead after conv2 LN)
    ushort* At   = (ushort*)x0;                // 81920 ushorts Toeplitz frags
    ushort* wqb  = (ushort*)(ws + 8454144);    // [512,512] bf16
    ushort* wkb  = (ushort*)(ws + 8585216);    // [512,512] bf16
    ushort* wvb  = (ushort*)(ws + 8716288);    // [512,512] bf16
    ushort* pwb  = (ushort*)(ws + 8847360);    // [512,512] bf16
    ushort* khi  = (ushort*)(ws + 8978432);    // [8,512,4,128] bf16 hi
    ushort* klo  = (ushort*)(ws + 10027008);   // [8,512,4,128] bf16 lo
    ushort* vTb  = (ushort*)(ws + 11075584);   // [32,128,512] bf16 v^T
    ushort* kvb  = (ushort*)x1;                // [8,512,512] bf16 (x1 dead after upsample)
    ushort* qhi  = (ushort*)z;                 // [8,1024,4,128] bf16 hi (qxb dead after gemm q)
    ushort* qlo  = (ushort*)(ws + 2097152);    // [8,1024,4,128] bf16 lo (z region, after qhi)
    // attn0b spans the dead q+k+v fp32 regions: 14680064..23068672 = 8388608 floats
    //   = [32,1024,512] ushorts exactly. q/k fp32 dead after freq_split_norm, v after vT_cvt,
    //   all preceding scores_mfma (the writer).
    ushort* attn0b = (ushort*)(ws + 14680064);
    ushort* xpb  = (ushort*)attn0;             // [8,1024,512] bf16 (attn0 dead after score_conv)
    ushort* ab   = (ushort*)(ws + 25214976);   // [32,1024,512] bf16 attn plane (after xpb,
                                               //  ends 33603584 < 39895040 ✓)

    float* out_x    = (float*)d_out;                    // [8,2048,512]
    float* out_attn = out_x + (size_t)8 * 2048 * 512;   // [8,4,2048,512]

    // precision casts / weight transforms
    cvt_bf16_k<<<8192, 256, 0, stream>>>(q_x, xtb, 2097152);
    wcvt_k<<<3072, 256, 0, stream>>>(qds_w, wc1b);
    wcvt_k<<<3072, 256, 0, stream>>>(qp_w, wc2b);
    // conv1 (MFMA) + LN + maxpool -> x0
    conv_mfma<<<dim3(16, 4, 8), 256, 0, stream>>>(xtb, wc1b, qds_b, z, 2048);
    ln_stats_k<<<dim3(32, 8), 256, 0, stream>>>(z, stats1, 2048);
    ln_maxpool_k<<<16384, 256, 0, stream>>>(z, stats1, qds_g, qds_be, x0, 2048, 10);
    // conv2 input transpose+cvt, conv2 (MFMA) + LN + maxpool -> x1
    transpose_cvt_k<<<dim3(32, 16, 8), 256, 0, stream>>>(x0, x0tb);
    conv_mfma<<<dim3(8, 4, 8), 256, 0, stream>>>(x0tb, wc2b, qp_b, z, 1024);
    ln_stats_k<<<dim3(16, 8), 256, 0, stream>>>(z, stats2, 1024);
    ln_maxpool_k<<<8192, 256, 0, stream>>>(z, stats2, qp_g, qp_be, x1, 1024, 9);
    // out = x0 + upsample2(x1), transpose to [B,1024,512] bf16 (into dead z region)
    upsample_add_t<<<16384, 256, 0, stream>>>(x0, x1, qxb);
    // Toeplitz A-fragments + bf16 weight casts (into dead x0 region), kv cast (dead x1)
    atoep_k<<<320, 256, 0, stream>>>(sw, At);
    wcvt4_k<<<1024, 256, 0, stream>>>(wq, wk, wv, pw, wqb, wkb, wvb, pwb);
    cvt_bf16_k<<<2048, 256, 0, stream>>>(kv_x, kvb, 524288);
    // projections (bf16 MFMA, fp32 accumulate); q/k raw (freq fused into split below)
    gemm_mfma_bf16<<<dim3(4, 64), 256, 0, stream>>>(qxb, wqb, nullptr, q, 8192, 512, 512, 0);
    gemm_mfma_bf16<<<dim3(4, 32), 256, 0, stream>>>(kvb, wkb, nullptr, k, 4096, 512, 512, 0);
    gemm_mfma_bf16<<<dim3(4, 32), 256, 0, stream>>>(kvb, wvb, nullptr, v, 4096, 512, 512, 0);
    // fused freq-add + hi/lo split + row norms (vectorized float4)
    freq_split_norm_k<<<4096, 256, 0, stream>>>(q, qf, qhi, qlo, q2, 10, 1);
    freq_split_norm_k<<<2048, 256, 0, stream>>>(k, kf, khi, klo, k2, 9, 0);
    // v^T bf16 for attn@v MFMA (v fp32 dead after this -> attn0b may overwrite)
    vT_cvt_k<<<dim3(16, 4, 32), 256, 0, stream>>>(v, vTb);
    // gaussian scores (bf16 MFMA, hi/lo compensated), dual-write fp32 + bf16
    scores_mfma<<<dim3(4, 8, 32), 256, 0, stream>>>(qhi, qlo, khi, klo, q2, k2,
                                                    attn0, attn0b);
    // score conv (MFMA, j-tile 32, bf16 staging, dj-unrolled) + bias + mask
    score_conv_mfma<<<dim3(16, 16, 8), 256, 0, stream>>>(attn0, attn0b, At, sb, mask, attn1);
    // softmax + prior fusion + renorm; fp32 duplicated rows -> d_out, bf16 plane -> ab
    softmax_prior_k<<<8192, 256, 0, stream>>>(attn1, prior, out_attn, ab);
    // attn @ v (bf16 MFMA from ab) -> bf16 xpb
    attnv_mfma<<<dim3(1, 8, 32), 256, 0, stream>>>(ab, vTb, xpb);
    // final projection (bf16 MFMA) with row duplication into d_out xout
    gemm_mfma_bf16<<<dim3(4, 64), 256, 0, stream>>>(xpb, pwb, pb, out_x, 8192, 512, 512, 1);
}

// Round 10
// 737.294 us; speedup vs baseline: 1.0388x; 1.0388x over previous
//
#include <hip/hip_runtime.h>
#include <math.h>

#define PS_CONST 0.31622776601683794f  // sqrt(0.1)

typedef __attribute__((ext_vector_type(8))) short short8;   // 8 bf16 (4 VGPRs)
typedef __attribute__((ext_vector_type(4))) float f32x4;

__device__ inline unsigned short f2b(float f) {
    unsigned u = __builtin_bit_cast(unsigned, f);
    unsigned r = (u + 0x7fffu + ((u >> 16) & 1u)) >> 16;   // RNE
    return (unsigned short)r;
}
__device__ inline float b2f(unsigned short b) {
    return __builtin_bit_cast(float, (unsigned)b << 16);
}

// fp32 -> bf16 elementwise (vectorized x4)
__global__ __launch_bounds__(256) void cvt_bf16_k(const float* __restrict__ in,
                                                  ushort* __restrict__ out, int n4)
{
    int idx = blockIdx.x * 256 + threadIdx.x;
    if (idx >= n4) return;
    float4 vv = ((const float4*)in)[idx];
    ushort4 o;
    o.x = f2b(vv.x); o.y = f2b(vv.y); o.z = f2b(vv.z); o.w = f2b(vv.w);
    ((ushort4*)out)[idx] = o;
}

// ---------------------------------------------------------------------------
// Fused: freq-add + hi/lo bf16 split + row(128) squared-norm.
// X: [B, L, 4, 128] fp32 (raw projection, no freq). F: freq table.
//   x' = X + PS * F[b, dupf ? 2l+1 : l, d]
//   hi/lo = bf16 split of x';  out2[(b*4+h)<<lishift | l] = sum_d x'^2
// One thread per float4; 32 consecutive threads cover one 128-d row.
// ---------------------------------------------------------------------------
__global__ __launch_bounds__(256) void freq_split_norm_k(
    const float* __restrict__ X, const float* __restrict__ F,
    ushort* __restrict__ hi, ushort* __restrict__ lo, float* __restrict__ out2,
    int lishift, int dupf)
{
    int idx = blockIdx.x * 256 + threadIdx.x;   // float4 index, exact multiple
    int f = idx << 2;
    int d = f & 127;
    int h = (f >> 7) & 3;
    int l = (f >> 9) & ((1 << lishift) - 1);
    int b = f >> (lishift + 9);
    int fr = dupf ? (2 * l + 1) : l;
    int fF = dupf ? (2 << lishift) : (1 << lishift);
    float4 xv = *(const float4*)&X[(size_t)f];
    float4 fv = *(const float4*)&F[((size_t)b * fF + fr) * 128 + d];
    float vs[4] = {xv.x + PS_CONST * fv.x, xv.y + PS_CONST * fv.y,
                   xv.z + PS_CONST * fv.z, xv.w + PS_CONST * fv.w};
    ushort4 hv, lv;
    unsigned short hb; float hf;
    hb = f2b(vs[0]); hf = b2f(hb); hv.x = hb; lv.x = f2b(vs[0] - hf);
    hb = f2b(vs[1]); hf = b2f(hb); hv.y = hb; lv.y = f2b(vs[1] - hf);
    hb = f2b(vs[2]); hf = b2f(hb); hv.z = hb; lv.z = f2b(vs[2] - hf);
    hb = f2b(vs[3]); hf = b2f(hb); hv.w = hb; lv.w = f2b(vs[3] - hf);
    ((ushort4*)hi)[idx] = hv;
    ((ushort4*)lo)[idx] = lv;
    float s = vs[0] * vs[0] + vs[1] * vs[1] + vs[2] * vs[2] + vs[3] * vs[3];
    #pragma unroll
    for (int off = 16; off > 0; off >>= 1) s += __shfl_xor(s, off);  // 32-lane row group
    if ((threadIdx.x & 31) == 0)
        out2[(((size_t)b * 4 + h) << lishift) + l] = s;
}

// weight transform: out[c][tap*512 + i] = bf16(w[c][i][3] at [c*1536 + i*3 + tap])
__global__ __launch_bounds__(256) void wcvt_k(const float* __restrict__ w,
                                              ushort* __restrict__ out)
{
    int idx = blockIdx.x * 256 + threadIdx.x;   // 786432
    if (idx >= 786432) return;
    int c = idx / 1536;
    int rem = idx - c * 1536;
    int tap = rem >> 9, i = rem & 511;
    out[idx] = f2b(w[c * 1536 + i * 3 + tap]);
}

// fused bf16 cast of the four 512x512 projection weights
__global__ __launch_bounds__(256) void wcvt4_k(
    const float* __restrict__ w0, const float* __restrict__ w1,
    const float* __restrict__ w2, const float* __restrict__ w3,
    ushort* __restrict__ o0, ushort* __restrict__ o1,
    ushort* __restrict__ o2, ushort* __restrict__ o3)
{
    int idx = blockIdx.x * 256 + threadIdx.x;   // 4 * 65536 float4
    int sel = idx >> 16, off = idx & 65535;
    const float* w = (sel == 0) ? w0 : (sel == 1) ? w1 : (sel == 2) ? w2 : w3;
    ushort* o = (sel == 0) ? o0 : (sel == 1) ? o1 : (sel == 2) ? o2 : o3;
    float4 vv = ((const float4*)w)[off];
    ushort4 r;
    r.x = f2b(vv.x); r.y = f2b(vv.y); r.z = f2b(vv.z); r.w = f2b(vv.w);
    ((ushort4*)o)[off] = r;
}

// Toeplitz A-fragment precompute for score conv MFMA.
__global__ __launch_bounds__(256) void atoep_k(const float* __restrict__ sw,
                                               ushort* __restrict__ At)
{
    int idx = blockIdx.x * 256 + threadIdx.x;   // 81920
    if (idx >= 81920) return;
    int t = idx & 7;
    int lane = (idx >> 3) & 63;
    int ks = (idx >> 9) & 1;
    int rem = idx >> 10;        // 0..79
    int dj = rem % 5, ohi = rem / 5;
    int m = lane & 15;
    int k = ks * 32 + ((lane >> 4) << 3) + t;
    int d = k - m;
    float val = (d >= 0 && d < 45) ? sw[(ohi * 45 + d) * 5 + dj] : 0.f;
    At[idx] = f2b(val);
}

// ---------------------------------------------------------------------------
// conv1d(512->512,k3,SAME) + bias + silu as MFMA bf16 GEMM.
// ---------------------------------------------------------------------------
__global__ __launch_bounds__(256) void conv_mfma(
    const ushort* __restrict__ xtb, const ushort* __restrict__ wtb,
    const float* __restrict__ cb, float* __restrict__ z, int L)
{
    __shared__ __align__(16) ushort Ash[128 * 40];
    __shared__ __align__(16) ushort Bsh[128 * 40];
    const int b = blockIdx.z;
    const int cm = blockIdx.y << 7;
    const int l0 = blockIdx.x << 7;
    const int tid = threadIdx.x;
    const int wave = tid >> 6, lane = tid & 63;
    const int wm = (wave & 1) << 6, wn = (wave >> 1) << 6;
    const int lo16 = lane & 15, hi4 = lane >> 4;

    f32x4 acc[4][4];
    #pragma unroll
    for (int i = 0; i < 4; i++)
        #pragma unroll
        for (int j = 0; j < 4; j++)
            acc[i][j] = (f32x4){0.f, 0.f, 0.f, 0.f};

    for (int k0 = 0; k0 < 1536; k0 += 32) {
        const int tap = k0 >> 9;
        const int cbase = k0 & 511;
        {
            int u = tid;
            #pragma unroll
            for (int p = 0; p < 2; p++, u += 256) {
                int row = u >> 2, g = (u & 3) << 3;
                *(uint4*)&Ash[row * 40 + g] =
                    *(const uint4*)&wtb[(size_t)(cm + row) * 1536 + k0 + g];
            }
        }
        {
            int u = tid;
            #pragma unroll
            for (int p = 0; p < 2; p++, u += 256) {
                int row = u >> 2, g = (u & 3) << 3;
                int lg = l0 + tap - 1 + row;
                uint4 val = make_uint4(0u, 0u, 0u, 0u);
                if (lg >= 0 && lg < L)
                    val = *(const uint4*)&xtb[((size_t)b * L + lg) * 512 + cbase + g];
                *(uint4*)&Bsh[row * 40 + g] = val;
            }
        }
        __syncthreads();
        short8 a[4], bb[4];
        #pragma unroll
        for (int t = 0; t < 4; t++) {
            a[t]  = *(const short8*)&Ash[(wm + t * 16 + lo16) * 40 + hi4 * 8];
            bb[t] = *(const short8*)&Bsh[(wn + t * 16 + lo16) * 40 + hi4 * 8];
        }
        #pragma unroll
        for (int mt = 0; mt < 4; mt++)
            #pragma unroll
            for (int nt = 0; nt < 4; nt++)
                acc[mt][nt] = __builtin_amdgcn_mfma_f32_16x16x32_bf16(
                    a[mt], bb[nt], acc[mt][nt], 0, 0, 0);
        __syncthreads();
    }
    #pragma unroll
    for (int mt = 0; mt < 4; mt++) {
        #pragma unroll
        for (int r = 0; r < 4; r++) {
            int c = cm + wm + mt * 16 + hi4 * 4 + r;
            float bias = cb[c];
            #pragma unroll
            for (int nt = 0; nt < 4; nt++) {
                int l = l0 + wn + nt * 16 + lo16;
                float u = acc[mt][nt][r] + bias;
                u = u / (1.f + __expf(-u));
                z[((size_t)b * 512 + c) * L + l] = u;
            }
        }
    }
}

// ---------------------------------------------------------------------------
// Y[M,N] fp32 = Xb[M,K]bf16 @ Wb[N,K]bf16^T (+bias), MFMA, 128x128 tile.
// dup: write row m -> rows 2m, 2m+1.
// ---------------------------------------------------------------------------
__global__ __launch_bounds__(256) void gemm_mfma_bf16(
    const ushort* __restrict__ Xb, const ushort* __restrict__ Wb,
    const float* __restrict__ bias, float* __restrict__ Y,
    int M, int N, int K, int dup)
{
    __shared__ __align__(16) ushort Ash[128 * 40];
    __shared__ __align__(16) ushort Bsh[128 * 40];
    const int bm = blockIdx.y << 7, bn = blockIdx.x << 7;
    const int tid = threadIdx.x;
    const int wave = tid >> 6, lane = tid & 63;
    const int wm = (wave & 1) << 6, wn = (wave >> 1) << 6;
    const int lo16 = lane & 15, hi4 = lane >> 4;

    f32x4 acc[4][4];
    #pragma unroll
    for (int i = 0; i < 4; i++)
        #pragma unroll
        for (int j = 0; j < 4; j++)
            acc[i][j] = (f32x4){0.f, 0.f, 0.f, 0.f};

    for (int k0 = 0; k0 < K; k0 += 32) {
        int u = tid;
        #pragma unroll
        for (int p = 0; p < 2; p++, u += 256) {
            int row = u >> 2, g = (u & 3) << 3;
            *(uint4*)&Ash[row * 40 + g] =
                *(const uint4*)&Xb[(size_t)(bm + row) * K + k0 + g];
            *(uint4*)&Bsh[row * 40 + g] =
                *(const uint4*)&Wb[(size_t)(bn + row) * K + k0 + g];
        }
        __syncthreads();
        short8 a[4], bb[4];
        #pragma unroll
        for (int t = 0; t < 4; t++) {
            a[t]  = *(const short8*)&Ash[(wm + t * 16 + lo16) * 40 + hi4 * 8];
            bb[t] = *(const short8*)&Bsh[(wn + t * 16 + lo16) * 40 + hi4 * 8];
        }
        #pragma unroll
        for (int mt = 0; mt < 4; mt++)
            #pragma unroll
            for (int nt = 0; nt < 4; nt++)
                acc[mt][nt] = __builtin_amdgcn_mfma_f32_16x16x32_bf16(
                    a[mt], bb[nt], acc[mt][nt], 0, 0, 0);
        __syncthreads();
    }
    #pragma unroll
    for (int mt = 0; mt < 4; mt++) {
        #pragma unroll
        for (int r = 0; r < 4; r++) {
            int m = bm + wm + mt * 16 + hi4 * 4 + r;
            #pragma unroll
            for (int nt = 0; nt < 4; nt++) {
                int n = bn + wn + nt * 16 + lo16;
                float val = acc[mt][nt][r];
                if (bias) val += bias[n];
                if (dup) {
                    Y[(size_t)(2 * m)     * N + n] = val;
                    Y[(size_t)(2 * m + 1) * N + n] = val;
                } else {
                    Y[(size_t)m * N + n] = val;
                }
            }
        }
    }
}

// per-column LN stats over 512 channels: stats[b][l] = (mean, rsqrt(var+eps))
__global__ __launch_bounds__(256) void ln_stats_k(const float* __restrict__ z,
                                                  float2* __restrict__ stats, int L)
{
    __shared__ float s_sh[4][64];
    __shared__ float s2_sh[4][64];
    const int b = blockIdx.y;
    const int colL = threadIdx.x & 63;
    const int col = (blockIdx.x << 6) + colL;
    const int part = threadIdx.x >> 6;
    const float* base = z + ((size_t)b * 512 + part * 128) * L + col;
    float s = 0.f, s2 = 0.f;
    for (int i = 0; i < 128; i++) {
        float vv = base[(size_t)i * L];
        s += vv; s2 += vv * vv;
    }
    s_sh[part][colL] = s; s2_sh[part][colL] = s2;
    __syncthreads();
    if (threadIdx.x < 64) {
        float ts = 0.f, ts2 = 0.f;
        #pragma unroll
        for (int p = 0; p < 4; p++) { ts += s_sh[p][colL]; ts2 += s2_sh[p][colL]; }
        float m = ts * (1.f / 512.f);
        float var = ts2 * (1.f / 512.f) - m * m;
        stats[(size_t)b * L + col] = make_float2(m, rsqrtf(var + 1e-5f));
    }
}

// LN apply + maxpool(k3,s2,pad -inf): out[b][c][lp], Lout = L/2 = 1<<lshift
__global__ __launch_bounds__(256) void ln_maxpool_k(
    const float* __restrict__ z, const float2* __restrict__ stats,
    const float* __restrict__ g, const float* __restrict__ be,
    float* __restrict__ out, int L, int lshift)
{
    const int Lout = 1 << lshift;
    size_t idx = (size_t)blockIdx.x * 256 + threadIdx.x;  // 8*512*Lout
    int lp = (int)(idx & (Lout - 1));
    int c = (int)((idx >> lshift) & 511);
    int b = (int)(idx >> (lshift + 9));
    const float* zp = z + ((size_t)b * 512 + c) * L;
    const float2* sp = stats + (size_t)b * L;
    float gc = g[c], bc = be[c];
    int l = lp << 1;
    float2 st = sp[l];
    float m = (zp[l] - st.x) * st.y * gc + bc;
    if (l > 0) {
        float2 s0 = sp[l - 1];
        m = fmaxf(m, (zp[l - 1] - s0.x) * s0.y * gc + bc);
    }
    float2 s1 = sp[l + 1];
    m = fmaxf(m, (zp[l + 1] - s1.x) * s1.y * gc + bc);
    out[idx] = m;
}

// x0 [B][512][1024] fp32 -> x0tb [B][1024][512] bf16 (tiled transpose + cvt)
__global__ __launch_bounds__(256) void transpose_cvt_k(const float* __restrict__ x0,
                                                       ushort* __restrict__ xtb)
{
    __shared__ ushort t[32][33];
    const int b = blockIdx.z, c0 = blockIdx.y << 5, l0 = blockIdx.x << 5;
    const int col = threadIdx.x & 31, r0 = threadIdx.x >> 5;
    #pragma unroll
    for (int p = 0; p < 4; p++) {
        int r = r0 + p * 8;
        t[r][col] = f2b(x0[((size_t)b * 512 + c0 + r) * 1024 + l0 + col]);
    }
    __syncthreads();
    #pragma unroll
    for (int p = 0; p < 4; p++) {
        int r = r0 + p * 8;
        xtb[((size_t)b * 1024 + l0 + r) * 512 + c0 + col] = t[col][r];
    }
}

// vTb[bh][d][j] bf16 = v[b][j][h][d]  (tiled transpose + cvt, per head)
__global__ __launch_bounds__(256) void vT_cvt_k(const float* __restrict__ v,
                                                ushort* __restrict__ vTb)
{
    __shared__ ushort t[32][33];
    const int bh = blockIdx.z, b = bh >> 2, h = bh & 3;
    const int d0 = blockIdx.y << 5, j0 = blockIdx.x << 5;
    const int col = threadIdx.x & 31, r0 = threadIdx.x >> 5;
    #pragma unroll
    for (int p = 0; p < 4; p++) {
        int r = r0 + p * 8;   // j offset
        t[r][col] = f2b(v[(((size_t)b * 512 + j0 + r) * 4 + h) * 128 + d0 + col]);
    }
    __syncthreads();
    #pragma unroll
    for (int p = 0; p < 4; p++) {
        int r = r0 + p * 8;   // d offset
        vTb[((size_t)bh * 128 + d0 + r) * 512 + j0 + col] = t[col][r];
    }
}

// qxb[b, l, c] = bf16( x0[b, c, l] + x1[b, c, l>>1] )  (upsample-add + transpose + cast)
__global__ __launch_bounds__(256) void upsample_add_t(const float* __restrict__ x0,
    const float* __restrict__ x1, ushort* __restrict__ qxb)
{
    size_t idx = (size_t)blockIdx.x * 256 + threadIdx.x;  // 8*1024*512
    int c = (int)(idx & 511);
    int l = (int)((idx >> 9) & 1023);
    int b = (int)(idx >> 19);
    qxb[idx] = f2b(x0[((size_t)b * 512 + c) * 1024 + l] +
                   x1[((size_t)b * 512 + c) * 512 + (l >> 1)]);
}

// ---------------------------------------------------------------------------
// Gaussian scores via bf16 MFMA with hi/lo error compensation.
// attn0[bh,i,j] = -clip((q2+k2-2*q.k)/128, 0) / temp[h]
// Dual-write: fp32 attn0 (for conv residual) + bf16 attn0b (for conv staging).
// ---------------------------------------------------------------------------
__global__ __launch_bounds__(256) void scores_mfma(
    const ushort* __restrict__ qhi, const ushort* __restrict__ qlo,
    const ushort* __restrict__ khi, const ushort* __restrict__ klo,
    const float* __restrict__ q2, const float* __restrict__ k2,
    float* __restrict__ attn0, ushort* __restrict__ attn0b)
{
    __shared__ __align__(16) ushort Ah[128 * 40];
    __shared__ __align__(16) ushort Al[128 * 40];
    __shared__ __align__(16) ushort Bh[128 * 40];
    __shared__ __align__(16) ushort Bl[128 * 40];
    const int bh = blockIdx.z, b = bh >> 2, h = bh & 3;
    const int bm = blockIdx.y << 7, bn = blockIdx.x << 7;
    const int tid = threadIdx.x;
    const int wave = tid >> 6, lane = tid & 63;
    const int wm = (wave & 1) << 6, wn = (wave >> 1) << 6;
    const int lo16 = lane & 15, hi4 = lane >> 4;

    f32x4 acc[4][4];
    #pragma unroll
    for (int i = 0; i < 4; i++)
        #pragma unroll
        for (int j = 0; j < 4; j++)
            acc[i][j] = (f32x4){0.f, 0.f, 0.f, 0.f};

    for (int k0 = 0; k0 < 128; k0 += 32) {
        int u = tid;
        #pragma unroll
        for (int p = 0; p < 2; p++, u += 256) {
            int row = u >> 2, g = (u & 3) << 3;
            size_t aoff = (((size_t)b * 1024 + bm + row) * 4 + h) * 128 + k0 + g;
            size_t boff = (((size_t)b * 512  + bn + row) * 4 + h) * 128 + k0 + g;
            *(uint4*)&Ah[row * 40 + g] = *(const uint4*)&qhi[aoff];
            *(uint4*)&Al[row * 40 + g] = *(const uint4*)&qlo[aoff];
            *(uint4*)&Bh[row * 40 + g] = *(const uint4*)&khi[boff];
            *(uint4*)&Bl[row * 40 + g] = *(const uint4*)&klo[boff];
        }
        __syncthreads();
        short8 ah[4], al[4], bhF[4], blF[4];
        #pragma unroll
        for (int t = 0; t < 4; t++) {
            int ar = (wm + t * 16 + lo16) * 40 + hi4 * 8;
            int br = (wn + t * 16 + lo16) * 40 + hi4 * 8;
            ah[t]  = *(const short8*)&Ah[ar];
            al[t]  = *(const short8*)&Al[ar];
            bhF[t] = *(const short8*)&Bh[br];
            blF[t] = *(const short8*)&Bl[br];
        }
        #pragma unroll
        for (int mt = 0; mt < 4; mt++)
            #pragma unroll
            for (int nt = 0; nt < 4; nt++) {
                acc[mt][nt] = __builtin_amdgcn_mfma_f32_16x16x32_bf16(
                    ah[mt], bhF[nt], acc[mt][nt], 0, 0, 0);
                acc[mt][nt] = __builtin_amdgcn_mfma_f32_16x16x32_bf16(
                    ah[mt], blF[nt], acc[mt][nt], 0, 0, 0);
                acc[mt][nt] = __builtin_amdgcn_mfma_f32_16x16x32_bf16(
                    al[mt], bhF[nt], acc[mt][nt], 0, 0, 0);
            }
        __syncthreads();
    }
    const float it = (h == 0) ? 1.f : (h == 1) ? 0.25f : (h == 2) ? (1.f / 7.f) : 0.1f;
    #pragma unroll
    for (int mt = 0; mt < 4; mt++) {
        #pragma unroll
        for (int r = 0; r < 4; r++) {
            int i = bm + wm + mt * 16 + hi4 * 4 + r;
            float q2v = q2[(size_t)bh * 1024 + i];
            #pragma unroll
            for (int nt = 0; nt < 4; nt++) {
                int j = bn + wn + nt * 16 + lo16;
                float d2 = q2v + k2[(size_t)bh * 512 + j] - 2.f * acc[mt][nt][r];
                d2 *= (1.f / 128.f);
                if (d2 < 0.f) d2 = 0.f;
                float sc = -d2 * it;
                size_t off = ((size_t)bh * 1024 + i) * 512 + j;
                attn0[off]  = sc;
                attn0b[off] = f2b(sc);
            }
        }
    }
}

// ---------------------------------------------------------------------------
// Conv2d(4,4,(45,5),pad(22,2)) via MFMA (Toeplitz along i).
// j-tile 32, 4 blocks/CU; staging from bf16 attn0b (half bytes, no cvt).
// tileT[hi][jj<36][ii<112, stride 120]. Grid (16, 16, 8).
// dj loop kept at unroll 1 — R9 showed the unrolled form regresses (135 vs 108).
// ---------------------------------------------------------------------------
__global__ __launch_bounds__(256) void score_conv_mfma(
    const float* __restrict__ attn0, const ushort* __restrict__ attn0b,
    const ushort* __restrict__ At, const float* __restrict__ sb,
    const float* __restrict__ mask, float* __restrict__ attn1)
{
    __shared__ __align__(16) ushort tileT[4 * 36 * 120];   // [hi][jj][ii], ii stride 120
    const int b = blockIdx.z, i0 = blockIdx.y << 6, j0 = blockIdx.x << 5;
    const int tid = threadIdx.x, wave = tid >> 6, lane = tid & 63;

    for (int idx = tid; idx < 4 * 36 * 56; idx += 256) {
        int jj = idx % 36;
        int r2 = idx / 36;
        int ip = r2 % 56, hi = r2 / 56;
        int ii = ip << 1;
        int gi = i0 - 22 + ii, gj = j0 - 2 + jj;
        const ushort* src = attn0b + ((size_t)(b * 4 + hi) * 1024 + gi) * 512 + gj;
        bool jv = (unsigned)gj < 512u;
        unsigned v0 = (jv && (unsigned)gi       < 1024u) ? (unsigned)src[0]   : 0u;
        unsigned v1 = (jv && (unsigned)(gi + 1) < 1024u) ? (unsigned)src[512] : 0u;
        *(unsigned*)&tileT[(hi * 36 + jj) * 120 + ii] = v0 | (v1 << 16);
    }
    __syncthreads();

    const int n16 = lane & 15, quad = lane >> 4;
    f32x4 acc[4][2];
    #pragma unroll
    for (int o = 0; o < 4; o++)
        #pragma unroll
        for (int t = 0; t < 2; t++)
            acc[o][t] = (f32x4){0.f, 0.f, 0.f, 0.f};

    const int iibase = wave * 16 + quad * 8;
    #pragma unroll 1
    for (int hi = 0; hi < 4; hi++) {
        #pragma unroll 1
        for (int dj = 0; dj < 5; dj++) {
            #pragma unroll
            for (int ks = 0; ks < 2; ks++) {
                short8 bf[2];
                #pragma unroll
                for (int t = 0; t < 2; t++)
                    bf[t] = *(const short8*)&tileT[(hi * 36 + t * 16 + n16 + dj) * 120
                                                   + iibase + ks * 32];
                #pragma unroll
                for (int o = 0; o < 4; o++) {
                    short8 af = *(const short8*)&At[((((o * 4 + hi) * 5 + dj) * 2 + ks) * 64
                                                     + lane) * 8];
                    #pragma unroll
                    for (int t = 0; t < 2; t++)
                        acc[o][t] = __builtin_amdgcn_mfma_f32_16x16x32_bf16(
                            af, bf[t], acc[o][t], 0, 0, 0);
                }
            }
        }
    }

    #pragma unroll
    for (int o = 0; o < 4; o++) {
        float bo = sb[o];
        #pragma unroll
        for (int r = 0; r < 4; r++) {
            int i = i0 + wave * 16 + quad * 4 + r;
            size_t obase = ((size_t)(b * 4 + o) * 1024 + i) * 512;
            size_t mbase = ((size_t)b * 1024 + i) * 512;
            #pragma unroll
            for (int t = 0; t < 2; t++) {
                int j = j0 + t * 16 + n16;
                attn1[obase + j] = attn0[obase + j] + acc[o][t][r] + bo + mask[mbase + j];
            }
        }
    }
}

// softmax(row) -> clip -> * clip(prior) -> renorm; write rows 2i,2i+1 fp32
// plus a non-duplicated bf16 plane for the attn@v MFMA.
__global__ __launch_bounds__(256) void softmax_prior_k(
    const float* __restrict__ attn1, const float* __restrict__ prior,
    float* __restrict__ attn_out, ushort* __restrict__ ab)
{
    const int wid = threadIdx.x >> 6, lane = threadIdx.x & 63;
    size_t row = (size_t)blockIdx.x * 4 + wid;   // 0..32767
    int i = (int)(row & 1023);
    int bh = (int)(row >> 10);
    int b = bh >> 2;
    const float* arow = attn1 + row * 512;
    const float* prow = prior + ((size_t)b * 2048 + 2 * i + 1) * 512;
    float v[8], p[8];
    #pragma unroll
    for (int t = 0; t < 8; t++) {
        v[t] = arow[lane + 64 * t];
        p[t] = prow[lane + 64 * t];
    }
    float mx = v[0];
    #pragma unroll
    for (int t = 1; t < 8; t++) mx = fmaxf(mx, v[t]);
    #pragma unroll
    for (int off = 32; off > 0; off >>= 1) mx = fmaxf(mx, __shfl_xor(mx, off));
    float sum = 0.f;
    #pragma unroll
    for (int t = 0; t < 8; t++) { v[t] = expf(v[t] - mx); sum += v[t]; }
    #pragma unroll
    for (int off = 32; off > 0; off >>= 1) sum += __shfl_xor(sum, off);
    float inv = 1.f / sum;
    float sum2 = 0.f;
    #pragma unroll
    for (int t = 0; t < 8; t++) {
        float sm = fmaxf(v[t] * inv, 1e-8f);
        float pr = fmaxf(p[t], 1e-8f);
        v[t] = sm * pr;
        sum2 += v[t];
    }
    #pragma unroll
    for (int off = 32; off > 0; off >>= 1) sum2 += __shfl_xor(sum2, off);
    float inv2 = 1.f / (sum2 + 1e-8f);
    float* o0 = attn_out + ((size_t)bh * 2048 + 2 * i) * 512;
    ushort* abrow = ab + row * 512;
    #pragma unroll
    for (int t = 0; t < 8; t++) {
        float val = v[t] * inv2;
        o0[lane + 64 * t] = val;
        o0[512 + lane + 64 * t] = val;
        abrow[lane + 64 * t] = f2b(val);
    }
}

// ---------------------------------------------------------------------------
// attn @ v via bf16 MFMA from the non-duplicated bf16 plane:
// xpb[b,i,h*128+d] = bf16( sum_j ab[bh,i,j] * vT[bh,d,j] )
// M=1024 (i), N=128 (d, covered by waves), K=512 (j). Grid (1, 8, 32).
// ---------------------------------------------------------------------------
__global__ __launch_bounds__(256) void attnv_mfma(
    const ushort* __restrict__ ab, const ushort* __restrict__ vTb,
    ushort* __restrict__ xpb)
{
    __shared__ __align__(16) ushort Ash[128 * 40];
    __shared__ __align__(16) ushort Bsh[128 * 40];
    const int bh = blockIdx.z, b = bh >> 2, h = bh & 3;
    const int bm = blockIdx.y << 7;
    const ushort* A = ab + (size_t)bh * 1024 * 512;
    const ushort* B = vTb + (size_t)bh * 128 * 512;
    const int tid = threadIdx.x;
    const int wave = tid >> 6, lane = tid & 63;
    const int wm = (wave & 1) << 6, wn = (wave >> 1) << 6;
    const int lo16 = lane & 15, hi4 = lane >> 4;

    f32x4 acc[4][4];
    #pragma unroll
    for (int i = 0; i < 4; i++)
        #pragma unroll
        for (int j = 0; j < 4; j++)
            acc[i][j] = (f32x4){0.f, 0.f, 0.f, 0.f};

    for (int k0 = 0; k0 < 512; k0 += 32) {
        int u = tid;
        #pragma unroll
        for (int p = 0; p < 2; p++, u += 256) {
            int row = u >> 2, g = (u & 3) << 3;
            *(uint4*)&Ash[row * 40 + g] = *(const uint4*)&A[(size_t)(bm + row) * 512 + k0 + g];
            *(uint4*)&Bsh[row * 40 + g] = *(const uint4*)&B[(size_t)row * 512 + k0 + g];
        }
        __syncthreads();
        short8 a[4], bb[4];
        #pragma unroll
        for (int t = 0; t < 4; t++) {
            a[t]  = *(const short8*)&Ash[(wm + t * 16 + lo16) * 40 + hi4 * 8];
            bb[t] = *(const short8*)&Bsh[(wn + t * 16 + lo16) * 40 + hi4 * 8];
        }
        #pragma unroll
        for (int mt = 0; mt < 4; mt++)
            #pragma unroll
            for (int nt = 0; nt < 4; nt++)
                acc[mt][nt] = __builtin_amdgcn_mfma_f32_16x16x32_bf16(
                    a[mt], bb[nt], acc[mt][nt], 0, 0, 0);
        __syncthreads();
    }
    #pragma unroll
    for (int mt = 0; mt < 4; mt++) {
        #pragma unroll
        for (int r = 0; r < 4; r++) {
            int m = bm + wm + mt * 16 + hi4 * 4 + r;
            #pragma unroll
            for (int nt = 0; nt < 4; nt++) {
                int n = wn + nt * 16 + lo16;
                xpb[((size_t)b * 1024 + m) * 512 + h * 128 + n] = f2b(acc[mt][nt][r]);
            }
        }
    }
}

extern "C" void kernel_launch(void* const* d_in, const int* in_sizes, int n_in,
                              void* d_out, int out_size, void* d_ws, size_t ws_size,
                              hipStream_t stream)
{
    const float* q_x    = (const float*)d_in[0];
    const float* kv_x   = (const float*)d_in[1];
    const float* qf     = (const float*)d_in[2];
    const float* kf     = (const float*)d_in[3];
    const float* mask   = (const float*)d_in[4];
    const float* prior  = (const float*)d_in[5];
    const float* qds_w  = (const float*)d_in[6];
    const float* qds_b  = (const float*)d_in[7];
    const float* qds_g  = (const float*)d_in[8];
    const float* qds_be = (const float*)d_in[9];
    const float* qp_w   = (const float*)d_in[10];   // only layer 0 used (xs[2] is dead)
    const float* qp_b   = (const float*)d_in[11];
    const float* qp_g   = (const float*)d_in[12];
    const float* qp_be  = (const float*)d_in[13];
    const float* wq     = (const float*)d_in[14];
    const float* wk     = (const float*)d_in[15];
    const float* wv     = (const float*)d_in[16];
    const float* sw     = (const float*)d_in[17];
    const float* sb     = (const float*)d_in[18];
    const float* pw     = (const float*)d_in[19];
    const float* pb     = (const float*)d_in[20];

    if (ws_size < (size_t)56672256 * 4) return;
    float* ws = (float*)d_ws;
    float* z     = ws;               // [8,512,2048]; later qxb, then qhi/qlo
    float* x0    = ws + 8388608;     // [8,512,1024]; later At + weights + khi/klo/vTb
    float* x1    = ws + 12582912;    // [8,512,512];  later kvb (bf16)
    float* q     = ws + 14680064;    // [8,1024,4,128]; later attn0b (with k,v regions)
    float* k     = ws + 18874368;    // [8,512,4,128]
    float* v     = ws + 20971520;    // [8,512,4,128]
    float* q2    = ws + 23068672;    // [32,1024]
    float* k2    = ws + 23101440;    // [32,512]
    float* attn0 = ws + 23117824;    // [8,4,1024,512]; later xpb + ab (bf16)
    float* attn1 = ws + 39895040;    // [8,4,1024,512]
    // early-phase buffers aliased INSIDE attn1 region (dead before score_conv writes attn1)
    ushort* xtb   = (ushort*)(ws + 39895040);            // [8,2048,512] bf16
    ushort* x0tb  = (ushort*)(ws + 39895040 + 4194304);  // [8,1024,512] bf16
    ushort* wc1b  = (ushort*)(ws + 39895040 + 6291456);  // [512,1536] bf16
    ushort* wc2b  = (ushort*)(ws + 39895040 + 6684672);  // [512,1536] bf16
    float2* stats1 = (float2*)(ws + 39895040 + 7077888); // [8,2048]
    float2* stats2 = (float2*)(ws + 39895040 + 7110656); // [8,1024]
    // mid-phase bf16 buffers in the dead x0/z/x1 regions (float offsets, all disjoint):
    //   At    8388608..8429568 | wqb 8454144..8585216 | wkb ..8716288 | wvb ..8847360
    //   pwb   8847360..8978432 | khi 8978432..10027008 | klo ..11075584 | vTb ..12124160
    ushort* qxb  = (ushort*)z;                 // [8,1024,512] bf16 (z dead after conv2 LN)
    ushort* At   = (ushort*)x0;                // 81920 ushorts Toeplitz frags
    ushort* wqb  = (ushort*)(ws + 8454144);    // [512,512] bf16
    ushort* wkb  = (ushort*)(ws + 8585216);    // [512,512] bf16
    ushort* wvb  = (ushort*)(ws + 8716288);    // [512,512] bf16
    ushort* pwb  = (ushort*)(ws + 8847360);    // [512,512] bf16
    ushort* khi  = (ushort*)(ws + 8978432);    // [8,512,4,128] bf16 hi
    ushort* klo  = (ushort*)(ws + 10027008);   // [8,512,4,128] bf16 lo
    ushort* vTb  = (ushort*)(ws + 11075584);   // [32,128,512] bf16 v^T
    ushort* kvb  = (ushort*)x1;                // [8,512,512] bf16 (x1 dead after upsample)
    ushort* qhi  = (ushort*)z;                 // [8,1024,4,128] bf16 hi (qxb dead after gemm q)
    ushort* qlo  = (ushort*)(ws + 2097152);    // [8,1024,4,128] bf16 lo (z region, after qhi)
    // attn0b spans the dead q+k+v fp32 regions: 14680064..23068672 = 8388608 floats
    //   = [32,1024,512] ushorts exactly. q/k fp32 dead after freq_split_norm, v after vT_cvt,
    //   all preceding scores_mfma (the writer).
    ushort* attn0b = (ushort*)(ws + 14680064);
    ushort* xpb  = (ushort*)attn0;             // [8,1024,512] bf16 (attn0 dead after score_conv)
    ushort* ab   = (ushort*)(ws + 25214976);   // [32,1024,512] bf16 attn plane (after xpb,
                                               //  ends 33603584 < 39895040 ✓)

    float* out_x    = (float*)d_out;                    // [8,2048,512]
    float* out_attn = out_x + (size_t)8 * 2048 * 512;   // [8,4,2048,512]

    // precision casts / weight transforms
    cvt_bf16_k<<<8192, 256, 0, stream>>>(q_x, xtb, 2097152);
    wcvt_k<<<3072, 256, 0, stream>>>(qds_w, wc1b);
    wcvt_k<<<3072, 256, 0, stream>>>(qp_w, wc2b);
    // conv1 (MFMA) + LN + maxpool -> x0
    conv_mfma<<<dim3(16, 4, 8), 256, 0, stream>>>(xtb, wc1b, qds_b, z, 2048);
    ln_stats_k<<<dim3(32, 8), 256, 0, stream>>>(z, stats1, 2048);
    ln_maxpool_k<<<16384, 256, 0, stream>>>(z, stats1, qds_g, qds_be, x0, 2048, 10);
    // conv2 input transpose+cvt, conv2 (MFMA) + LN + maxpool -> x1
    transpose_cvt_k<<<dim3(32, 16, 8), 256, 0, stream>>>(x0, x0tb);
    conv_mfma<<<dim3(8, 4, 8), 256, 0, stream>>>(x0tb, wc2b, qp_b, z, 1024);
    ln_stats_k<<<dim3(16, 8), 256, 0, stream>>>(z, stats2, 1024);
    ln_maxpool_k<<<8192, 256, 0, stream>>>(z, stats2, qp_g, qp_be, x1, 1024, 9);
    // out = x0 + upsample2(x1), transpose to [B,1024,512] bf16 (into dead z region)
    upsample_add_t<<<16384, 256, 0, stream>>>(x0, x1, qxb);
    // Toeplitz A-fragments + bf16 weight casts (into dead x0 region), kv cast (dead x1)
    atoep_k<<<320, 256, 0, stream>>>(sw, At);
    wcvt4_k<<<1024, 256, 0, stream>>>(wq, wk, wv, pw, wqb, wkb, wvb, pwb);
    cvt_bf16_k<<<2048, 256, 0, stream>>>(kv_x, kvb, 524288);
    // projections (bf16 MFMA, fp32 accumulate); q/k raw (freq fused into split below)
    gemm_mfma_bf16<<<dim3(4, 64), 256, 0, stream>>>(qxb, wqb, nullptr, q, 8192, 512, 512, 0);
    gemm_mfma_bf16<<<dim3(4, 32), 256, 0, stream>>>(kvb, wkb, nullptr, k, 4096, 512, 512, 0);
    gemm_mfma_bf16<<<dim3(4, 32), 256, 0, stream>>>(kvb, wvb, nullptr, v, 4096, 512, 512, 0);
    // fused freq-add + hi/lo split + row norms (vectorized float4)
    freq_split_norm_k<<<4096, 256, 0, stream>>>(q, qf, qhi, qlo, q2, 10, 1);
    freq_split_norm_k<<<2048, 256, 0, stream>>>(k, kf, khi, klo, k2, 9, 0);
    // v^T bf16 for attn@v MFMA (v fp32 dead after this -> attn0b may overwrite)
    vT_cvt_k<<<dim3(16, 4, 32), 256, 0, stream>>>(v, vTb);
    // gaussian scores (bf16 MFMA, hi/lo compensated), dual-write fp32 + bf16
    scores_mfma<<<dim3(4, 8, 32), 256, 0, stream>>>(qhi, qlo, khi, klo, q2, k2,
                                                    attn0, attn0b);
    // score conv (MFMA, j-tile 32, bf16 staging, dj unroll 1) + bias + mask
    score_conv_mfma<<<dim3(16, 16, 8), 256, 0, stream>>>(attn0, attn0b, At, sb, mask, attn1);
    // softmax + prior fusion + renorm; fp32 duplicated rows -> d_out, bf16 plane -> ab
    softmax_prior_k<<<8192, 256, 0, stream>>>(attn1, prior, out_attn, ab);
    // attn @ v (bf16 MFMA from ab) -> bf16 xpb
    attnv_mfma<<<dim3(1, 8, 32), 256, 0, stream>>>(ab, vTb, xpb);
    // final projection (bf16 MFMA) with row duplication into d_out xout
    gemm_mfma_bf16<<<dim3(4, 64), 256, 0, stream>>>(xpb, pwb, pb, out_x, 8192, 512, 512, 1);
}